// Round 8
// baseline (257.397 us; speedup 1.0000x reference)
//
#include <hip/hip_runtime.h>
#include <math.h>
#include <float.h>

#define K_CODES 8192
#define C_DIM   256
#define N_TOK   16384
#define B_      16
#define H_      32
#define W_      32
#define HW      1024
#define KSPLIT  16
#define TOKS_PER_BLK 256

typedef short  short8   __attribute__((ext_vector_type(8)));
typedef float  floatx16 __attribute__((ext_vector_type(16)));

__device__ inline ushort f32_to_bf16_rne(float x) {
    union { float f; unsigned u; } v; v.f = x;
    unsigned u = v.u;
    return (ushort)((u + 0x7FFFu + ((u >> 16) & 1u)) >> 16);
}
__device__ inline float bf16_bits_to_f32(ushort h) {
    union { unsigned u; float f; } v; v.u = ((unsigned)h) << 16;
    return v.f;
}
__device__ inline unsigned umax_(unsigned a, unsigned b) { return a > b ? a : b; }
__device__ inline unsigned umin_(unsigned a, unsigned b) { return a < b ? a : b; }

__device__ inline void g2l16(const void* g, void* l) {
    __builtin_amdgcn_global_load_lds((const __attribute__((address_space(1))) unsigned int*)g,
                                     (__attribute__((address_space(3))) unsigned int*)l,
                                     16, 0, 0);
}

// Swizzled bf16 layout for 32x32x16 MFMA frags (rows x 256 ch)  [verified r5]:
//   byte addr = RG*16384 + CB*1024 + hh*512 + r*16 + (ch&7)*2
//   (RG = row>>5, CB = ch>>4, hh = (ch>>3)&1, r = row&31)
// One frag (32 rows x 16 ch) = contiguous 1KB at RG*16384 + CB*1024; lane l
// (r = l&31, hh = l>>5) reads +l*16.

// ---------------------------------------------------------------------------
// Kernel 1 (fused): bid<256 -> codebook (32 codes): e_n fp32, s2, swizzled
// Chi/Clo. bid>=256 -> tokens ((b,h), 32 tokens): ztn fp32, swizzled Thi/Tlo.
// (verbatim round-5 norm_pack — correctness-verified there)
// ---------------------------------------------------------------------------
__global__ __launch_bounds__(256) void norm_pack(
        const float* __restrict__ emb, const float* __restrict__ z,
        float* __restrict__ e_n, float* __restrict__ s2,
        ushort* __restrict__ Chi, ushort* __restrict__ Clo,
        float* __restrict__ ztn, ushort* __restrict__ Thi, ushort* __restrict__ Tlo) {
    __shared__ float tile[32][257];
    __shared__ float pvt[32][9];
    __shared__ float pvt2[32][9];
    __shared__ float inv[32];
    int t = threadIdx.x;
    int bid = blockIdx.x;
    if (bid < 256) {
        int k0 = bid * 32;
        int r = t >> 3, cp = t & 7;
        const float* src = emb + (size_t)(k0 + r) * C_DIM + cp * 32;
        float ss = 0.f;
        #pragma unroll
        for (int j = 0; j < 8; ++j) {
            float4 v = *(const float4*)(src + j * 4);
            tile[r][cp * 32 + j * 4 + 0] = v.x;
            tile[r][cp * 32 + j * 4 + 1] = v.y;
            tile[r][cp * 32 + j * 4 + 2] = v.z;
            tile[r][cp * 32 + j * 4 + 3] = v.w;
            ss = fmaf(v.x, v.x, ss); ss = fmaf(v.y, v.y, ss);
            ss = fmaf(v.z, v.z, ss); ss = fmaf(v.w, v.w, ss);
        }
        pvt[r][cp] = ss;
        __syncthreads();
        if (t < 32) {
            float a = 0.f;
            #pragma unroll
            for (int p = 0; p < 8; ++p) a += pvt[t][p];
            inv[t] = 1.0f / fmaxf(sqrtf(a), 1e-12f);
        }
        __syncthreads();
        float iv = inv[r];
        float s2p = 0.f;
        float* dst = e_n + (size_t)(k0 + r) * C_DIM + cp * 32;
        #pragma unroll
        for (int j = 0; j < 8; ++j) {
            float a = tile[r][cp * 32 + j * 4 + 0] * iv;
            float b = tile[r][cp * 32 + j * 4 + 1] * iv;
            float c = tile[r][cp * 32 + j * 4 + 2] * iv;
            float d = tile[r][cp * 32 + j * 4 + 3] * iv;
            s2p = fmaf(a, a, s2p); s2p = fmaf(b, b, s2p);
            s2p = fmaf(c, c, s2p); s2p = fmaf(d, d, s2p);
            float4 o = {a, b, c, d};
            *(float4*)(dst + j * 4) = o;
        }
        pvt2[r][cp] = s2p;
        __syncthreads();
        if (t < 32) {
            float a = 0.f;
            #pragma unroll
            for (int p = 0; p < 8; ++p) a += pvt2[t][p];
            s2[k0 + t] = a;
        }
        char* chiB = (char*)Chi;
        char* cloB = (char*)Clo;
        #pragma unroll
        for (int e = 0; e < 4; ++e) {
            int p = e * 256 + t;
            int row = p & 31;
            int ch0 = ((p >> 6) << 4) | (((p >> 5) & 1) << 3);
            float rv = inv[row];
            union { ushort u[8]; uint4 v; } hs, ls;
            #pragma unroll
            for (int i = 0; i < 8; ++i) {
                float vv = tile[row][ch0 + i] * rv;
                ushort hb = f32_to_bf16_rne(vv);
                hs.u[i] = hb;
                ls.u[i] = f32_to_bf16_rne(vv - bf16_bits_to_f32(hb));
            }
            size_t addr = (size_t)bid * 16384 + (size_t)p * 16;
            *(uint4*)(chiB + addr) = hs.v;
            *(uint4*)(cloB + addr) = ls.v;
        }
    } else {
        int tb = bid - 256;            // b*32 + h, RG = tb
        int b = tb >> 5, h = tb & 31;
        int w = t & 31, c0 = t >> 5;
        const float* zb = z + ((size_t)(b * C_DIM) * H_ + h) * W_;
        #pragma unroll
        for (int it = 0; it < 32; ++it) {
            int c = it * 8 + c0;
            tile[w][c] = zb[(size_t)c * HW + w];
        }
        __syncthreads();
        int part = t >> 5, w2 = t & 31;
        float s = 0.f;
        #pragma unroll
        for (int i = 0; i < 32; ++i) {
            float v = tile[w2][part * 32 + i];
            s = fmaf(v, v, s);
        }
        pvt[w2][part] = s;
        __syncthreads();
        if (t < 32) {
            float ss = 0.f;
            #pragma unroll
            for (int p = 0; p < 8; ++p) ss += pvt[t][p];
            inv[t] = 1.0f / fmaxf(sqrtf(ss), 1e-12f);
        }
        __syncthreads();
        int n_base = tb * 32;
        for (int r = 0; r < 32; ++r) {
            float val = tile[r][t] * inv[r];
            ztn[(size_t)(n_base + r) * C_DIM + t] = val;
        }
        char* thiB = (char*)Thi;
        char* tloB = (char*)Tlo;
        #pragma unroll
        for (int e = 0; e < 4; ++e) {
            int p = e * 256 + t;
            int row = p & 31;
            int ch0 = ((p >> 6) << 4) | (((p >> 5) & 1) << 3);
            float rv = inv[row];
            union { ushort u[8]; uint4 v; } hs, ls;
            #pragma unroll
            for (int i = 0; i < 8; ++i) {
                float vv = tile[row][ch0 + i] * rv;
                ushort hb = f32_to_bf16_rne(vv);
                hs.u[i] = hb;
                ls.u[i] = f32_to_bf16_rne(vv - bf16_bits_to_f32(hb));
            }
            size_t addr = (size_t)tb * 16384 + (size_t)p * 16;
            *(uint4*)(thiB + addr) = hs.v;
            *(uint4*)(tloB + addr) = ls.v;
        }
    }
}

// ---------------------------------------------------------------------------
// Kernel 2: MFMA scan, 32x32x16 bf16, single-barrier ping-pong pipeline.
// Block 256 thr / 4 waves; tile 256 tok x 128 codes; wave = 64 tok x 128
// codes (CT=4, NT=2, acc 128 VGPR). Stage = 16 channels = 24KB (codes 8 +
// tokens 16), double-buffered (48KB). Per stage: ONE __syncthreads (the
// buffer's DMA was issued a full compute-phase earlier -> drain ~free),
// then prefetch next stage into the other buffer, then 24 MFMAs.
// Grid (64, 16). D layout: col=lane&31=token, row=(reg&3)+8*(reg>>2)+4*(l>>5).
// ---------------------------------------------------------------------------
__global__ __launch_bounds__(256, 2) void score_topk(
        const ushort* __restrict__ Chi, const ushort* __restrict__ Clo,
        const ushort* __restrict__ Thi, const ushort* __restrict__ Tlo,
        uint4* __restrict__ cand) {
    __shared__ __align__(16) char smem[49152];   // buf0 @0, buf1 @24576
    int t = threadIdx.x;
    int l = t & 63, wv = t >> 6;
    int hh = l >> 5, col = l & 31;
    int tokBase = blockIdx.x * TOKS_PER_BLK;
    int tokRG = tokBase >> 5;                // 8 token RG32s per block
    int part = blockIdx.y;
    int partBase = part * (K_CODES / KSPLIT);   // 512 codes per partition
    int codeRGbase = partBase >> 5;

    const char* chiB = (const char*)Chi;
    const char* cloB = (const char*)Clo;
    const char* thiB = (const char*)Thi;
    const char* tloB = (const char*)Tlo;

    unsigned rv1[2] = {0u, 0u}, rv2[2] = {0u, 0u};
    int ri1[2] = {0, 0}, ri2[2] = {0, 0};

    // stage(kt, s) -> buf: 24 slices of 1KB, 6 per wave
    auto stage = [&](int skt, int ss, char* buf) {
        int codeRG = codeRGbase + skt * 4;
        #pragma unroll
        for (int gi = 0; gi < 6; ++gi) {
            int slice = wv * 6 + gi;
            const char* gb;
            int off;
            if (slice < 8) {
                int hilo = slice & 1, crg = slice >> 1;
                gb = (hilo ? cloB : chiB) + (size_t)(codeRG + crg) * 16384;
                off = ((hilo << 2) + crg) << 10;
            } else {
                int sl = slice - 8;
                int hilo = sl & 1, trg = sl >> 1;
                gb = (hilo ? tloB : thiB) + (size_t)(tokRG + trg) * 16384;
                off = 8192 + (((hilo << 3) + trg) << 10);
            }
            g2l16(gb + ss * 1024 + (l << 4), buf + off);
        }
    };

    stage(0, 0, smem);                       // prologue into buf0

    for (int kt = 0; kt < 4; ++kt) {
        floatx16 acc[4][2];
        #pragma unroll
        for (int ct = 0; ct < 4; ++ct)
            #pragma unroll
            for (int nt = 0; nt < 2; ++nt)
                #pragma unroll
                for (int r = 0; r < 16; ++r) acc[ct][nt][r] = 0.f;

        for (int s = 0; s < 16; ++s) {
            int gidx = kt * 16 + s;
            __syncthreads();                 // current buf ready; prev readers done
            int nidx = gidx + 1;
            if (nidx < 64)
                stage(nidx >> 4, nidx & 15, smem + ((nidx & 1) ? 24576 : 0));
            const char* buf = smem + ((gidx & 1) ? 24576 : 0);

            short8 bh[2], bl[2];
            #pragma unroll
            for (int nt = 0; nt < 2; ++nt) {
                int trg = wv * 2 + nt;
                bh[nt] = *(const short8*)(buf + 8192 + (trg << 10) + (l << 4));
                bl[nt] = *(const short8*)(buf + 8192 + ((8 + trg) << 10) + (l << 4));
            }
            #pragma unroll
            for (int ct = 0; ct < 4; ++ct) {
                short8 ah = *(const short8*)(buf + (ct << 10) + (l << 4));
                short8 al = *(const short8*)(buf + ((4 + ct) << 10) + (l << 4));
                #pragma unroll
                for (int nt = 0; nt < 2; ++nt) {
                    acc[ct][nt] = __builtin_amdgcn_mfma_f32_32x32x16_bf16(al, bh[nt], acc[ct][nt], 0, 0, 0);
                    acc[ct][nt] = __builtin_amdgcn_mfma_f32_32x32x16_bf16(ah, bl[nt], acc[ct][nt], 0, 0, 0);
                    acc[ct][nt] = __builtin_amdgcn_mfma_f32_32x32x16_bf16(ah, bh[nt], acc[ct][nt], 0, 0, 0);
                }
            }
        }

        // packed-key top-2. key = (bits(d*0.25+1.25) & ~63) | (ct<<4 | reg)
        int kbase = partBase + kt * 128;
        #pragma unroll
        for (int nt = 0; nt < 2; ++nt) {
            unsigned m1 = 0u, m2 = 0u;
            #pragma unroll
            for (int ct = 0; ct < 4; ++ct) {
                #pragma unroll
                for (int r = 0; r < 16; ++r) {
                    unsigned key = (__float_as_uint(fmaf(acc[ct][nt][r], 0.25f, 1.25f)) & 0xFFFFFFC0u)
                                   | (unsigned)((ct << 4) | r);
                    m2 = umax_(m2, umin_(key, m1));
                    m1 = umax_(m1, key);
                }
            }
            int o1 = (int)(m1 & 63u), o2 = (int)(m2 & 63u);
            int r1 = o1 & 15, r2 = o2 & 15;
            int c1 = kbase + ((o1 >> 4) << 5) + (r1 & 3) + 8 * (r1 >> 2) + 4 * hh;
            int c2 = kbase + ((o2 >> 4) << 5) + (r2 & 3) + 8 * (r2 >> 2) + 4 * hh;
            if (m1 > rv1[nt]) {
                if (m2 > rv1[nt]) { rv2[nt] = m2; ri2[nt] = c2; }
                else              { rv2[nt] = rv1[nt]; ri2[nt] = ri1[nt]; }
                rv1[nt] = m1; ri1[nt] = c1;
            } else if (m1 > rv2[nt]) {
                rv2[nt] = m1; ri2[nt] = c1;
            }
        }
    }

    // merge across the 2 lane-halves per token (token = wv*64 + nt*32 + col)
    __syncthreads();
    unsigned* mk1 = (unsigned*)smem;            // [256][2]
    int*      mi1 = (int*)(smem + 2048);
    unsigned* mk2 = (unsigned*)(smem + 4096);
    int*      mi2 = (int*)(smem + 6144);
    #pragma unroll
    for (int nt = 0; nt < 2; ++nt) {
        int T = wv * 64 + nt * 32 + col;
        mk1[T * 2 + hh] = rv1[nt]; mi1[T * 2 + hh] = ri1[nt];
        mk2[T * 2 + hh] = rv2[nt]; mi2[T * 2 + hh] = ri2[nt];
    }
    __syncthreads();
    {
        unsigned b1k = 0u, b2k = 0u; int b1i = 0x7FFFFFFF, b2i = 0x7FFFFFFF;
        #pragma unroll
        for (int src = 0; src < 2; ++src) {
            unsigned k = mk1[t * 2 + src]; int i = mi1[t * 2 + src];
            if (k > b1k || (k == b1k && i < b1i)) { b2k = b1k; b2i = b1i; b1k = k; b1i = i; }
            else if (k > b2k || (k == b2k && i < b2i)) { b2k = k; b2i = i; }
            k = mk2[t * 2 + src]; i = mi2[t * 2 + src];
            if (k > b1k || (k == b1k && i < b1i)) { b2k = b1k; b2i = b1i; b1k = k; b1i = i; }
            else if (k > b2k || (k == b2k && i < b2i)) { b2k = k; b2i = i; }
        }
        uint4 o = {b1k, (unsigned)b1i, b2k, (unsigned)b2i};
        cand[(size_t)part * N_TOK + tokBase + t] = o;
    }
}

// ---------------------------------------------------------------------------
// Kernel 3: margin-gated rescore + gather. Block per (b,h) = 32 tokens.
// Merge 32 (key,idx) pairs (16 partitions x 2); if key1-key2 > 1024 ULP the
// scan decided -> no reads. Else exact fp32 rescore of 32 candidates reading
// ztn/e_n directly from global (L2-hot; ~2% of tokens). Then gather+transpose.
// ---------------------------------------------------------------------------
__global__ __launch_bounds__(256) void rescore_gather(
        const float* __restrict__ ztn, const float* __restrict__ e_n,
        const float* __restrict__ s2, const uint4* __restrict__ cand,
        float* __restrict__ out, float* __restrict__ idxf) {
    __shared__ __align__(16) char sm[32 * 257 * 4];
    __shared__ uint4 cd[32][16];
    __shared__ int idxs[32];
    __shared__ int slowlist[32];
    __shared__ int nslow;
    float* tile = (float*)sm;        // [32][257] (phase C)
    int t = threadIdx.x;
    int bid = blockIdx.x;            // b*32 + h
    int b = bid >> 5, h = bid & 31;
    int n_base = bid * 32;
    int wv = t >> 6, l = t & 63;

    if (t == 0) nslow = 0;
    {
        int tok = t >> 3, p = t & 7;
        cd[tok][p]     = cand[(size_t)p * N_TOK + n_base + tok];
        cd[tok][p + 8] = cand[(size_t)(p + 8) * N_TOK + n_base + tok];
    }
    __syncthreads();

    if (t < 32) {
        unsigned b1k = 0u, b2k = 0u; int b1i = 0x7FFFFFFF, b2i = 0x7FFFFFFF;
        #pragma unroll
        for (int p = 0; p < 16; ++p) {
            uint4 c4 = cd[t][p];
            unsigned k = c4.x; int i = (int)c4.y;
            if (k > b1k || (k == b1k && i < b1i)) { b2k = b1k; b2i = b1i; b1k = k; b1i = i; }
            else if (k > b2k || (k == b2k && i < b2i)) { b2k = k; b2i = i; }
            k = c4.z; i = (int)c4.w;
            if (k > b1k || (k == b1k && i < b1i)) { b2k = b1k; b2i = b1i; b1k = k; b1i = i; }
            else if (k > b2k || (k == b2k && i < b2i)) { b2k = k; b2i = i; }
        }
        if (b1k - b2k > 1024u) {        // scan-decided
            idxs[t] = b1i;
            idxf[n_base + t] = (float)b1i;
        } else {
            int s = atomicAdd(&nslow, 1);
            slowlist[s] = t;
        }
    }
    __syncthreads();
    int ns = nslow;
    // slow path: 32 candidates x 2 lanes each; operands direct from global
    int cs = l >> 1, p2 = l & 1;
    int prt = cs >> 1, slot = cs & 1;
    for (int j = wv; j < ns; j += 4) {
        int tok = slowlist[j];
        int n = n_base + tok;
        uint4 c4 = cd[tok][prt];
        int c = (int)(slot ? c4.w : c4.y);
        const float* er = e_n + (size_t)c * C_DIM + p2 * 128;
        const float* zr = ztn + (size_t)n * C_DIM + p2 * 128;
        float s = 0.f;
        #pragma unroll
        for (int jj = 0; jj < 32; ++jj) {
            float4 e4 = *(const float4*)(er + jj * 4);
            float4 z4 = *(const float4*)(zr + jj * 4);
            s = fmaf(e4.x, z4.x, s); s = fmaf(e4.y, z4.y, s);
            s = fmaf(e4.z, z4.z, s); s = fmaf(e4.w, z4.w, s);
        }
        s += __shfl_xor(s, 1);
        float bs = s2[c] - 2.f * s;
        int bi = c;
        #pragma unroll
        for (int d = 2; d < 64; d <<= 1) {
            float os = __shfl_xor(bs, d);
            int   oi = __shfl_xor(bi, d);
            if (os < bs || (os == bs && oi < bi)) { bs = os; bi = oi; }
        }
        if (l == 0) { idxs[tok] = bi; idxf[n] = (float)bi; }
    }
    __syncthreads();

    // Phase C: gather winning rows, transpose-write
    for (int r = 0; r < 32; ++r) {
        int k = idxs[r];
        tile[r * 257 + t] = e_n[(size_t)k * C_DIM + t];
    }
    __syncthreads();
    int w = t & 31, c0 = t >> 5;
    float* ob = out + ((size_t)(b * C_DIM) * H_ + h) * W_;
    #pragma unroll
    for (int it = 0; it < 32; ++it) {
        int c = it * 8 + c0;
        ob[(size_t)c * HW + w] = tile[w * 257 + c];
    }
}

// ---------------------------------------------------------------------------
extern "C" void kernel_launch(void* const* d_in, const int* in_sizes, int n_in,
                              void* d_out, int out_size, void* d_ws, size_t ws_size,
                              hipStream_t stream) {
    const float* z   = (const float*)d_in[0];
    const float* emb = (const float*)d_in[1];
    float* out  = (float*)d_out;
    float* idxf = out + (size_t)B_ * C_DIM * H_ * W_;

    char* ws = (char*)d_ws;
    size_t o = 0;
    float*  e_n  = (float*)(ws + o);  o += (size_t)K_CODES * C_DIM * 4;   // 8 MB
    float*  s2   = (float*)(ws + o);  o += 32768;
    float*  ztn  = (float*)(ws + o);  o += (size_t)N_TOK * C_DIM * 4;     // 16 MB
    ushort* Chi  = (ushort*)(ws + o); o += (size_t)K_CODES * C_DIM * 2;   // 4 MB
    ushort* Clo  = (ushort*)(ws + o); o += (size_t)K_CODES * C_DIM * 2;   // 4 MB
    ushort* Thi  = (ushort*)(ws + o); o += (size_t)N_TOK * C_DIM * 2;     // 8 MB
    ushort* Tlo  = (ushort*)(ws + o); o += (size_t)N_TOK * C_DIM * 2;     // 8 MB
    uint4*  cand = (uint4*)(ws + o);  o += (size_t)KSPLIT * N_TOK * 16;   // 4 MB

    hipLaunchKernelGGL(norm_pack, dim3(256 + B_ * H_), dim3(256), 0, stream,
                       emb, z, e_n, s2, Chi, Clo, ztn, Thi, Tlo);
    hipLaunchKernelGGL(score_topk, dim3(N_TOK / TOKS_PER_BLK, KSPLIT), dim3(256), 0, stream,
                       Chi, Clo, Thi, Tlo, cand);
    hipLaunchKernelGGL(rescore_gather, dim3(B_ * H_), dim3(256), 0, stream,
                       ztn, e_n, s2, cand, out, idxf);
}

// Round 9
// 220.564 us; speedup vs baseline: 1.1670x; 1.1670x over previous
//
#include <hip/hip_runtime.h>
#include <math.h>
#include <float.h>

#define K_CODES 8192
#define C_DIM   256
#define N_TOK   16384
#define B_      16
#define H_      32
#define W_      32
#define HW      1024
#define KSPLIT  16
#define TOKS_PER_BLK 256

typedef short  short8   __attribute__((ext_vector_type(8)));
typedef float  floatx16 __attribute__((ext_vector_type(16)));

__device__ inline ushort f32_to_bf16_rne(float x) {
    union { float f; unsigned u; } v; v.f = x;
    unsigned u = v.u;
    return (ushort)((u + 0x7FFFu + ((u >> 16) & 1u)) >> 16);
}
__device__ inline float bf16_bits_to_f32(ushort h) {
    union { unsigned u; float f; } v; v.u = ((unsigned)h) << 16;
    return v.f;
}
__device__ inline unsigned umax_(unsigned a, unsigned b) { return a > b ? a : b; }
__device__ inline unsigned umin_(unsigned a, unsigned b) { return a < b ? a : b; }

__device__ inline void g2l16(const void* g, void* l) {
    __builtin_amdgcn_global_load_lds((const __attribute__((address_space(1))) unsigned int*)g,
                                     (__attribute__((address_space(3))) unsigned int*)l,
                                     16, 0, 0);
}

// Swizzled bf16 layout for 32x32x16 MFMA frags (rows x 256 ch) [verified r5/r8]:
//   byte addr = RG*16384 + p*16, p = CB*64 + hh*32 + r
//   (RG = row>>5, CB = ch>>4, hh = (ch>>3)&1, r = row&31)
// One frag (32 rows x 16 ch) = contiguous 1KB; lane l (r=l&31, hh=l>>5) at +l*16.

// ---------------------------------------------------------------------------
// Kernel 1 (fused): bid<256 -> codebook (32 codes): e_n fp32, s2, swizzled
// Chi/Clo (hi AND lo). bid>=256 -> tokens: ztn fp32, swizzled Thi (hi ONLY —
// the 2-product scheme never consumes token-lo).
// ---------------------------------------------------------------------------
__global__ __launch_bounds__(256) void norm_pack(
        const float* __restrict__ emb, const float* __restrict__ z,
        float* __restrict__ e_n, float* __restrict__ s2,
        ushort* __restrict__ Chi, ushort* __restrict__ Clo,
        float* __restrict__ ztn, ushort* __restrict__ Thi) {
    __shared__ float tile[32][257];
    __shared__ float pvt[32][9];
    __shared__ float pvt2[32][9];
    __shared__ float inv[32];
    int t = threadIdx.x;
    int bid = blockIdx.x;
    if (bid < 256) {
        int k0 = bid * 32;
        int r = t >> 3, cp = t & 7;
        const float* src = emb + (size_t)(k0 + r) * C_DIM + cp * 32;
        float ss = 0.f;
        #pragma unroll
        for (int j = 0; j < 8; ++j) {
            float4 v = *(const float4*)(src + j * 4);
            tile[r][cp * 32 + j * 4 + 0] = v.x;
            tile[r][cp * 32 + j * 4 + 1] = v.y;
            tile[r][cp * 32 + j * 4 + 2] = v.z;
            tile[r][cp * 32 + j * 4 + 3] = v.w;
            ss = fmaf(v.x, v.x, ss); ss = fmaf(v.y, v.y, ss);
            ss = fmaf(v.z, v.z, ss); ss = fmaf(v.w, v.w, ss);
        }
        pvt[r][cp] = ss;
        __syncthreads();
        if (t < 32) {
            float a = 0.f;
            #pragma unroll
            for (int p = 0; p < 8; ++p) a += pvt[t][p];
            inv[t] = 1.0f / fmaxf(sqrtf(a), 1e-12f);
        }
        __syncthreads();
        float iv = inv[r];
        float s2p = 0.f;
        float* dst = e_n + (size_t)(k0 + r) * C_DIM + cp * 32;
        #pragma unroll
        for (int j = 0; j < 8; ++j) {
            float a = tile[r][cp * 32 + j * 4 + 0] * iv;
            float b = tile[r][cp * 32 + j * 4 + 1] * iv;
            float c = tile[r][cp * 32 + j * 4 + 2] * iv;
            float d = tile[r][cp * 32 + j * 4 + 3] * iv;
            s2p = fmaf(a, a, s2p); s2p = fmaf(b, b, s2p);
            s2p = fmaf(c, c, s2p); s2p = fmaf(d, d, s2p);
            float4 o = {a, b, c, d};
            *(float4*)(dst + j * 4) = o;
        }
        pvt2[r][cp] = s2p;
        __syncthreads();
        if (t < 32) {
            float a = 0.f;
            #pragma unroll
            for (int p = 0; p < 8; ++p) a += pvt2[t][p];
            s2[k0 + t] = a;
        }
        char* chiB = (char*)Chi;
        char* cloB = (char*)Clo;
        #pragma unroll
        for (int e = 0; e < 4; ++e) {
            int p = e * 256 + t;
            int row = p & 31;
            int ch0 = ((p >> 6) << 4) | (((p >> 5) & 1) << 3);
            float rv = inv[row];
            union { ushort u[8]; uint4 v; } hs, ls;
            #pragma unroll
            for (int i = 0; i < 8; ++i) {
                float vv = tile[row][ch0 + i] * rv;
                ushort hb = f32_to_bf16_rne(vv);
                hs.u[i] = hb;
                ls.u[i] = f32_to_bf16_rne(vv - bf16_bits_to_f32(hb));
            }
            size_t addr = (size_t)bid * 16384 + (size_t)p * 16;
            *(uint4*)(chiB + addr) = hs.v;
            *(uint4*)(cloB + addr) = ls.v;
        }
    } else {
        int tb = bid - 256;            // b*32 + h, RG = tb
        int b = tb >> 5, h = tb & 31;
        int w = t & 31, c0 = t >> 5;
        const float* zb = z + ((size_t)(b * C_DIM) * H_ + h) * W_;
        #pragma unroll
        for (int it = 0; it < 32; ++it) {
            int c = it * 8 + c0;
            tile[w][c] = zb[(size_t)c * HW + w];
        }
        __syncthreads();
        int part = t >> 5, w2 = t & 31;
        float s = 0.f;
        #pragma unroll
        for (int i = 0; i < 32; ++i) {
            float v = tile[w2][part * 32 + i];
            s = fmaf(v, v, s);
        }
        pvt[w2][part] = s;
        __syncthreads();
        if (t < 32) {
            float ss = 0.f;
            #pragma unroll
            for (int p = 0; p < 8; ++p) ss += pvt[t][p];
            inv[t] = 1.0f / fmaxf(sqrtf(ss), 1e-12f);
        }
        __syncthreads();
        int n_base = tb * 32;
        for (int r = 0; r < 32; ++r) {
            float val = tile[r][t] * inv[r];
            ztn[(size_t)(n_base + r) * C_DIM + t] = val;
        }
        char* thiB = (char*)Thi;
        #pragma unroll
        for (int e = 0; e < 4; ++e) {
            int p = e * 256 + t;
            int row = p & 31;
            int ch0 = ((p >> 6) << 4) | (((p >> 5) & 1) << 3);
            float rv = inv[row];
            union { ushort u[8]; uint4 v; } hs;
            #pragma unroll
            for (int i = 0; i < 8; ++i)
                hs.u[i] = f32_to_bf16_rne(tile[row][ch0 + i] * rv);
            size_t addr = (size_t)tb * 16384 + (size_t)p * 16;
            *(uint4*)(thiB + addr) = hs.v;
        }
    }
}

// ---------------------------------------------------------------------------
// Kernel 2: MFMA scan, 32x32x16 bf16, 2-product scheme:
//   dot ~= (c_hi + c_lo)·t_hi   (2 chained MFMAs per acc; err ~7e-5 on dot)
// Ping-pong pipeline (r8-verified): stage = 16 ch = 16KB (codes hi+lo 8KB +
// tokens hi 8KB), dbuf 32KB, ONE barrier/stage. Block 256 thr/4 waves; tile
// 256 tok x 128 codes; wave = 64 tok x 128 codes (CT=4, NT=2, acc 128 VGPR).
// Grid (64,16) = 4 blocks/CU, fully resident. Emits TOP-3 (key,idx) per
// token/partition (safety for the dropped product).
// ---------------------------------------------------------------------------
__global__ __launch_bounds__(256, 2) void score_topk(
        const ushort* __restrict__ Chi, const ushort* __restrict__ Clo,
        const ushort* __restrict__ Thi, uint2* __restrict__ cand) {
    __shared__ __align__(16) char smem[32768];   // buf0 @0, buf1 @16384
    int t = threadIdx.x;
    int l = t & 63, wv = t >> 6;
    int hh = l >> 5, col = l & 31;
    int tokBase = blockIdx.x * TOKS_PER_BLK;
    int tokRG = tokBase >> 5;                // 8 token RG32s per block
    int part = blockIdx.y;
    int partBase = part * (K_CODES / KSPLIT);   // 512 codes per partition
    int codeRGbase = partBase >> 5;

    const char* chiB = (const char*)Chi;
    const char* cloB = (const char*)Clo;
    const char* thiB = (const char*)Thi;

    unsigned rv1[2] = {0u, 0u}, rv2[2] = {0u, 0u}, rv3[2] = {0u, 0u};
    int ri1[2] = {0, 0}, ri2[2] = {0, 0}, ri3[2] = {0, 0};

    // stage(kt, s) -> buf: 16 slices of 1KB, 4 per wave
    auto stage = [&](int skt, int ss, char* buf) {
        int codeRG = codeRGbase + skt * 4;
        #pragma unroll
        for (int gi = 0; gi < 4; ++gi) {
            int slice = wv * 4 + gi;
            const char* gb;
            int off;
            if (slice < 8) {
                int hilo = slice & 1, crg = slice >> 1;
                gb = (hilo ? cloB : chiB) + (size_t)(codeRG + crg) * 16384;
                off = ((hilo << 2) + crg) << 10;
            } else {
                int trg = slice - 8;
                gb = thiB + (size_t)(tokRG + trg) * 16384;
                off = 8192 + (trg << 10);
            }
            g2l16(gb + ss * 1024 + (l << 4), buf + off);
        }
    };

    stage(0, 0, smem);                       // prologue into buf0

    for (int kt = 0; kt < 4; ++kt) {
        floatx16 acc[4][2];
        #pragma unroll
        for (int ct = 0; ct < 4; ++ct)
            #pragma unroll
            for (int nt = 0; nt < 2; ++nt)
                #pragma unroll
                for (int r = 0; r < 16; ++r) acc[ct][nt][r] = 0.f;

        for (int s = 0; s < 16; ++s) {
            int gidx = kt * 16 + s;
            __syncthreads();                 // current buf ready; prev readers done
            int nidx = gidx + 1;
            if (nidx < 64)
                stage(nidx >> 4, nidx & 15, smem + ((nidx & 1) ? 16384 : 0));
            const char* buf = smem + ((gidx & 1) ? 16384 : 0);

            short8 bh[2];
            #pragma unroll
            for (int nt = 0; nt < 2; ++nt) {
                int trg = wv * 2 + nt;
                bh[nt] = *(const short8*)(buf + 8192 + (trg << 10) + (l << 4));
            }
            #pragma unroll
            for (int ct = 0; ct < 4; ++ct) {
                short8 ah = *(const short8*)(buf + (ct << 10) + (l << 4));
                short8 al = *(const short8*)(buf + ((4 + ct) << 10) + (l << 4));
                #pragma unroll
                for (int nt = 0; nt < 2; ++nt) {
                    acc[ct][nt] = __builtin_amdgcn_mfma_f32_32x32x16_bf16(al, bh[nt], acc[ct][nt], 0, 0, 0);
                    acc[ct][nt] = __builtin_amdgcn_mfma_f32_32x32x16_bf16(ah, bh[nt], acc[ct][nt], 0, 0, 0);
                }
            }
        }

        // packed-key top-3. key = (bits(d*0.25+1.25) & ~63) | (ct<<4 | reg)
        int kbase = partBase + kt * 128;
        #pragma unroll
        for (int nt = 0; nt < 2; ++nt) {
            unsigned m1 = 0u, m2 = 0u, m3 = 0u;
            #pragma unroll
            for (int ct = 0; ct < 4; ++ct) {
                #pragma unroll
                for (int r = 0; r < 16; ++r) {
                    unsigned key = (__float_as_uint(fmaf(acc[ct][nt][r], 0.25f, 1.25f)) & 0xFFFFFFC0u)
                                   | (unsigned)((ct << 4) | r);
                    unsigned t1 = umin_(m1, key); m1 = umax_(m1, key);
                    unsigned t2 = umin_(m2, t1);  m2 = umax_(m2, t1);
                    m3 = umax_(m3, t2);
                }
            }
            unsigned mm[3] = {m1, m2, m3};
            #pragma unroll
            for (int j = 0; j < 3; ++j) {
                unsigned k = mm[j];
                int o = (int)(k & 63u), r = o & 15;
                int c = kbase + ((o >> 4) << 5) + (r & 3) + 8 * (r >> 2) + 4 * hh;
                if (k > rv1[nt]) {
                    rv3[nt] = rv2[nt]; ri3[nt] = ri2[nt];
                    rv2[nt] = rv1[nt]; ri2[nt] = ri1[nt];
                    rv1[nt] = k; ri1[nt] = c;
                } else if (k > rv2[nt]) {
                    rv3[nt] = rv2[nt]; ri3[nt] = ri2[nt];
                    rv2[nt] = k; ri2[nt] = c;
                } else if (k > rv3[nt]) {
                    rv3[nt] = k; ri3[nt] = c;
                }
            }
        }
    }

    // merge across the 2 lane-halves per token (token = wv*64 + nt*32 + col)
    __syncthreads();
    unsigned* mk = (unsigned*)smem;              // [256][6]
    int*      mi = (int*)(smem + 8192);
    #pragma unroll
    for (int nt = 0; nt < 2; ++nt) {
        int base = (wv * 64 + nt * 32 + col) * 6 + hh * 3;
        mk[base + 0] = rv1[nt]; mi[base + 0] = ri1[nt];
        mk[base + 1] = rv2[nt]; mi[base + 1] = ri2[nt];
        mk[base + 2] = rv3[nt]; mi[base + 2] = ri3[nt];
    }
    __syncthreads();
    {
        unsigned b1 = 0u, b2 = 0u, b3 = 0u;
        int i1 = 0x7FFFFFFF, i2 = 0x7FFFFFFF, i3 = 0x7FFFFFFF;
        #pragma unroll
        for (int j = 0; j < 6; ++j) {
            unsigned k = mk[t * 6 + j]; int i = mi[t * 6 + j];
            if (k > b1 || (k == b1 && i < i1)) {
                b3 = b2; i3 = i2; b2 = b1; i2 = i1; b1 = k; i1 = i;
            } else if (k > b2 || (k == b2 && i < i2)) {
                b3 = b2; i3 = i2; b2 = k; i2 = i;
            } else if (k > b3 || (k == b3 && i < i3)) {
                b3 = k; i3 = i;
            }
        }
        size_t base = ((size_t)part * N_TOK + tokBase + t) * 3;
        cand[base + 0] = {b1, (unsigned)i1};
        cand[base + 1] = {b2, (unsigned)i2};
        cand[base + 2] = {b3, (unsigned)i3};
    }
}

// ---------------------------------------------------------------------------
// Kernel 3: margin-gated rescore + gather. Block per (b,h) = 32 tokens.
// Merge 48 (key,idx) pairs (16 partitions x 3); if key1-key2 > 1024 ULP the
// scan decided (total scan err ~190 ULP incl. 64-ULP key quantization) ->
// done. Else exact fp32 rescore of 48 candidates (1 lane each), jnp.argmin
// tie semantics. Then gather + transpose-write.
// ---------------------------------------------------------------------------
__global__ __launch_bounds__(256) void rescore_gather(
        const float* __restrict__ ztn, const float* __restrict__ e_n,
        const float* __restrict__ s2, const uint2* __restrict__ cand,
        float* __restrict__ out, float* __restrict__ idxf) {
    __shared__ __align__(16) char sm[32 * 257 * 4];
    __shared__ uint2 cd[32][48];
    __shared__ int idxs[32];
    __shared__ int slowlist[32];
    __shared__ int nslow;
    float* tile = (float*)sm;        // [32][257] (phase C)
    int t = threadIdx.x;
    int bid = blockIdx.x;            // b*32 + h
    int b = bid >> 5, h = bid & 31;
    int n_base = bid * 32;
    int wv = t >> 6, l = t & 63;

    if (t == 0) nslow = 0;
    {
        int tok = t >> 3, p = t & 7;
        int n = n_base + tok;
        #pragma unroll
        for (int slot = 0; slot < 3; ++slot) {
            cd[tok][p * 3 + slot]        = cand[((size_t)p * N_TOK + n) * 3 + slot];
            cd[tok][(p + 8) * 3 + slot]  = cand[((size_t)(p + 8) * N_TOK + n) * 3 + slot];
        }
    }
    __syncthreads();

    if (t < 32) {
        unsigned b1k = 0u, b2k = 0u; int b1i = 0x7FFFFFFF, b2i = 0x7FFFFFFF;
        #pragma unroll
        for (int p = 0; p < 48; ++p) {
            uint2 c2 = cd[t][p];
            unsigned k = c2.x; int i = (int)c2.y;
            if (k > b1k || (k == b1k && i < b1i)) { b2k = b1k; b2i = b1i; b1k = k; b1i = i; }
            else if (k > b2k || (k == b2k && i < b2i)) { b2k = k; b2i = i; }
        }
        if (b1k - b2k > 1024u) {        // scan-decided
            idxs[t] = b1i;
            idxf[n_base + t] = (float)b1i;
        } else {
            int s = atomicAdd(&nslow, 1);
            slowlist[s] = t;
        }
    }
    __syncthreads();
    int ns = nslow;
    // slow path: 48 candidates, one lane each; operands direct from global
    for (int j = wv; j < ns; j += 4) {
        int tok = slowlist[j];
        int n = n_base + tok;
        float bs = FLT_MAX; int bi = 0x7FFFFFFF;
        if (l < 48) {
            int c = (int)cd[tok][l].y;
            const float* er = e_n + (size_t)c * C_DIM;
            const float* zr = ztn + (size_t)n * C_DIM;
            float s = 0.f;
            #pragma unroll
            for (int jj = 0; jj < 64; ++jj) {
                float4 e4 = *(const float4*)(er + jj * 4);
                float4 z4 = *(const float4*)(zr + jj * 4);
                s = fmaf(e4.x, z4.x, s); s = fmaf(e4.y, z4.y, s);
                s = fmaf(e4.z, z4.z, s); s = fmaf(e4.w, z4.w, s);
            }
            bs = s2[c] - 2.f * s;
            bi = c;
        }
        #pragma unroll
        for (int d = 1; d < 64; d <<= 1) {
            float os = __shfl_xor(bs, d);
            int   oi = __shfl_xor(bi, d);
            if (os < bs || (os == bs && oi < bi)) { bs = os; bi = oi; }
        }
        if (l == 0) { idxs[tok] = bi; idxf[n] = (float)bi; }
    }
    __syncthreads();

    // Phase C: gather winning rows, transpose-write
    for (int r = 0; r < 32; ++r) {
        int k = idxs[r];
        tile[r * 257 + t] = e_n[(size_t)k * C_DIM + t];
    }
    __syncthreads();
    int w = t & 31, c0 = t >> 5;
    float* ob = out + ((size_t)(b * C_DIM) * H_ + h) * W_;
    #pragma unroll
    for (int it = 0; it < 32; ++it) {
        int c = it * 8 + c0;
        ob[(size_t)c * HW + w] = tile[w * 257 + c];
    }
}

// ---------------------------------------------------------------------------
extern "C" void kernel_launch(void* const* d_in, const int* in_sizes, int n_in,
                              void* d_out, int out_size, void* d_ws, size_t ws_size,
                              hipStream_t stream) {
    const float* z   = (const float*)d_in[0];
    const float* emb = (const float*)d_in[1];
    float* out  = (float*)d_out;
    float* idxf = out + (size_t)B_ * C_DIM * H_ * W_;

    char* ws = (char*)d_ws;
    size_t o = 0;
    float*  e_n  = (float*)(ws + o);  o += (size_t)K_CODES * C_DIM * 4;   // 8 MB
    float*  s2   = (float*)(ws + o);  o += 32768;
    float*  ztn  = (float*)(ws + o);  o += (size_t)N_TOK * C_DIM * 4;     // 16 MB
    ushort* Chi  = (ushort*)(ws + o); o += (size_t)K_CODES * C_DIM * 2;   // 4 MB
    ushort* Clo  = (ushort*)(ws + o); o += (size_t)K_CODES * C_DIM * 2;   // 4 MB
    ushort* Thi  = (ushort*)(ws + o); o += (size_t)N_TOK * C_DIM * 2;     // 8 MB
    uint2*  cand = (uint2*)(ws + o);  o += (size_t)KSPLIT * N_TOK * 3 * 8; // 6 MB

    hipLaunchKernelGGL(norm_pack, dim3(256 + B_ * H_), dim3(256), 0, stream,
                       emb, z, e_n, s2, Chi, Clo, ztn, Thi);
    hipLaunchKernelGGL(score_topk, dim3(N_TOK / TOKS_PER_BLK, KSPLIT), dim3(256), 0, stream,
                       Chi, Clo, Thi, cand);
    hipLaunchKernelGGL(rescore_gather, dim3(B_ * H_), dim3(256), 0, stream,
                       ztn, e_n, s2, cand, out, idxf);
}